// Round 3
// baseline (428.712 us; speedup 1.0000x reference)
//
#include <hip/hip_runtime.h>

// OneToOneLinear: out = sigmoid(4 * (input * weight + bias)), per-feature w/b.
// N=32768 rows x F=2048 fp32. Pure streaming: 268 MB in + 268 MB out -> ~85us
// floor at 6.3 TB/s achievable HBM.
//
// Each thread owns ONE feature-column vector (float4-width) and strides over
// rows. w/b loaded once per thread (pre-scaled by -4), so the inner loop is:
// 1 nontemporal load, fma, exp, rcp, 1 nontemporal store. Consecutive tids ->
// consecutive columns -> fully coalesced. Nontemporal: zero reuse stream.
//
// NOTE: HIP's float4 is a struct; __builtin_nontemporal_* needs a native
// clang vector type -> use ext_vector_type(4).

typedef float fvec4 __attribute__((ext_vector_type(4)));

#define FEATURES     2048
#define NROWS        32768
#define VEC_PER_ROW  (FEATURES / 4)   // 512 float4 per row (pow2)
#define BLOCK        256
#define GRID         8192             // 2,097,152 threads = 4096 row-groups
#define ROW_STRIDE   ((GRID * BLOCK) / VEC_PER_ROW)  // 4096
#define ROWS_PER_T   (NROWS / ROW_STRIDE)            // 8

__global__ __launch_bounds__(BLOCK) void
OneToOneLinear_24807731102291_kernel(const fvec4* __restrict__ in,
                                     const fvec4* __restrict__ w,
                                     const fvec4* __restrict__ b,
                                     fvec4* __restrict__ out) {
    int tid = blockIdx.x * BLOCK + threadIdx.x;
    int c   = tid & (VEC_PER_ROW - 1);   // feature-vector column, fixed
    int r0  = tid >> 9;                  // starting row

    // sigmoid(4*(x*w+b)) = 1/(1+exp((-4w)*x + (-4b))) -- fold scale into w/b.
    fvec4 w4 = w[c] * -4.0f;
    fvec4 b4 = b[c] * -4.0f;

#pragma unroll
    for (int i = 0; i < ROWS_PER_T; ++i) {
        int idx = (r0 + i * ROW_STRIDE) * VEC_PER_ROW + c;  // < 2^24, 32-bit ok
        fvec4 x = __builtin_nontemporal_load(&in[idx]);
        fvec4 r;
        r.x = 1.0f / (1.0f + __expf(fmaf(x.x, w4.x, b4.x)));
        r.y = 1.0f / (1.0f + __expf(fmaf(x.y, w4.y, b4.y)));
        r.z = 1.0f / (1.0f + __expf(fmaf(x.z, w4.z, b4.z)));
        r.w = 1.0f / (1.0f + __expf(fmaf(x.w, w4.w, b4.w)));
        __builtin_nontemporal_store(r, &out[idx]);
    }
}

extern "C" void kernel_launch(void* const* d_in, const int* in_sizes, int n_in,
                              void* d_out, int out_size, void* d_ws, size_t ws_size,
                              hipStream_t stream) {
    const fvec4* in = (const fvec4*)d_in[0];   // (N, FEATURES) fp32
    const fvec4* w  = (const fvec4*)d_in[1];   // (FEATURES,)   fp32
    const fvec4* b  = (const fvec4*)d_in[2];   // (FEATURES,)   fp32
    fvec4* out      = (fvec4*)d_out;

    OneToOneLinear_24807731102291_kernel<<<GRID, BLOCK, 0, stream>>>(in, w, b, out);
}